// Round 3
// baseline (79.593 us; speedup 1.0000x reference)
//
#include <hip/hip_runtime.h>

// B=8, N=512, D=64, E=32
// ws layout: src = ws[0 .. 4096*32), dst = ws[4096*32 .. 2*4096*32)  (1 MB)
#define BNE (4096 * 32)

// Kernel 1: src/dst projections. One wave per row; x-row pointer uniform
// (blockIdx-only). lane = (proj, e). Folds be into src, inits out = br.
__global__ __launch_bounds__(64) void proj_kernel(
    const float* __restrict__ x, const float* __restrict__ We,
    const float* __restrict__ be, const float* __restrict__ br,
    float* __restrict__ out, float* __restrict__ ws)
{
    const int lane = threadIdx.x;          // 0..63
    const int row  = blockIdx.x;           // 0..4095 = b*512 + i (uniform)
    const int proj = lane >> 5;            // 0 = src, 1 = dst
    const int e    = lane & 31;

    const float* __restrict__ xrow = x + (size_t)row * 64;        // uniform
    const float* __restrict__ wcol = We + proj * (64 * 32) + e;   // coalesced

    float acc = 0.0f;
    #pragma unroll
    for (int d = 0; d < 64; ++d)
        acc = fmaf(xrow[d], wcol[d * 32], acc);

    if (proj == 0) acc += be[e];

    ws[(size_t)proj * BNE + (size_t)row * 32 + e] = acc;

    if (blockIdx.x < 64) out[blockIdx.x * 64 + lane] = br[0];
}

// Kernel 2: delta[b,j] += sum_{i,e} relu(src[b,i,e]+dst[b,j,e]) * Wr[i*32+e]
// 128 threads/block, FOUR j's per thread (j = t + {0,128,256,384}):
// 12 VALU ops per 2 wave-uniform scalars; float4 uniform loads (broadcast);
// 4 independent FMA chains. Grid (128 i-tiles of 4, 8 batches) = 2048 waves.
__global__ __launch_bounds__(128, 2) void edge_kernel(
    const float* __restrict__ ws, const float* __restrict__ Wr,
    float* __restrict__ out)
{
    const float* __restrict__ src = ws;
    const float* __restrict__ dst = ws + BNE;

    const int t  = threadIdx.x;            // 0..127
    const int b  = blockIdx.y;             // 0..7
    const int i0 = blockIdx.x * 4;         // 0..508

    // dst[b, j, 0..31] for 4 j's -> 128 VGPRs
    float d[4][32];
    #pragma unroll
    for (int jj = 0; jj < 4; ++jj) {
        const int j = t + jj * 128;
        const float4* __restrict__ dp =
            (const float4*)(dst + ((size_t)(b * 512 + j)) * 32);
        #pragma unroll
        for (int k = 0; k < 8; ++k) {
            const float4 v = dp[k];
            d[jj][k * 4 + 0] = v.x;
            d[jj][k * 4 + 1] = v.y;
            d[jj][k * 4 + 2] = v.z;
            d[jj][k * 4 + 3] = v.w;
        }
    }

    float acc[4] = {0.f, 0.f, 0.f, 0.f};

    #pragma unroll
    for (int ii = 0; ii < 4; ++ii) {
        const int i = i0 + ii;
        const float4* __restrict__ s4 =
            (const float4*)(src + ((size_t)(b * 512 + i)) * 32);   // uniform
        const float4* __restrict__ w4 =
            (const float4*)(Wr + (size_t)i * 32);                  // uniform
        #pragma unroll
        for (int q = 0; q < 8; ++q) {
            const float4 s = s4[q];
            const float4 w = w4[q];
            const int e = q * 4;
            #pragma unroll
            for (int jj = 0; jj < 4; ++jj) {
                acc[jj] = fmaf(fmaxf(s.x + d[jj][e + 0], 0.f), w.x, acc[jj]);
                acc[jj] = fmaf(fmaxf(s.y + d[jj][e + 1], 0.f), w.y, acc[jj]);
                acc[jj] = fmaf(fmaxf(s.z + d[jj][e + 2], 0.f), w.z, acc[jj]);
                acc[jj] = fmaf(fmaxf(s.w + d[jj][e + 3], 0.f), w.w, acc[jj]);
            }
        }
    }

    #pragma unroll
    for (int jj = 0; jj < 4; ++jj)
        atomicAdd(&out[b * 512 + t + jj * 128], acc[jj]);
}

extern "C" void kernel_launch(void* const* d_in, const int* in_sizes, int n_in,
                              void* d_out, int out_size, void* d_ws, size_t ws_size,
                              hipStream_t stream) {
    const float* x  = (const float*)d_in[0];   // (8,512,64)
    const float* We = (const float*)d_in[1];   // (128,32)
    const float* be = (const float*)d_in[2];   // (32,)
    const float* Wr = (const float*)d_in[3];   // (16384,1)
    const float* br = (const float*)d_in[4];   // (1,)
    float* out = (float*)d_out;                // (8,512,1) = 4096 floats
    float* ws  = (float*)d_ws;

    proj_kernel<<<4096, 64, 0, stream>>>(x, We, be, br, out, ws);
    edge_kernel<<<dim3(128, 8), 128, 0, stream>>>(ws, Wr, out);
}